// Round 1
// baseline (2028.448 us; speedup 1.0000x reference)
//
#include <hip/hip_runtime.h>
#include <cstdint>
#include <cstddef>

#define DIM 128
#define NEG_SLOPE 0.2f

// ---------------------------------------------------------------------------
// GEMM: Y[rows x 128] = X[rows x 128] @ W[128 x 128], fp32.
// Whole W staged in LDS (64 KB); 32 rows per block; 4 rows x 4 cols per thread.
// ---------------------------------------------------------------------------
__global__ __launch_bounds__(256) void gemm128_kernel(
    const float* __restrict__ X, const float* __restrict__ W,
    float* __restrict__ Y, int rows)
{
  __shared__ float Wl[128 * 128];
  __shared__ float Xl[32 * 128];
  int tid = threadIdx.x;
  {
    const float4* W4 = (const float4*)W;
    float4* Wl4 = (float4*)Wl;
#pragma unroll
    for (int i = 0; i < 16; ++i) Wl4[tid + i * 256] = W4[tid + i * 256];
  }
  int r0 = blockIdx.x * 32;
  int nrow = rows - r0; if (nrow > 32) nrow = 32;
  {
    const float4* X4 = (const float4*)(X + (size_t)r0 * DIM);
    float4* Xl4 = (float4*)Xl;
    for (int i = tid; i < nrow * 32; i += 256) Xl4[i] = X4[i];
  }
  __syncthreads();
  int rq = (tid >> 5) << 2;    // row quad base within block: 0,4,...,28
  int dg = (tid & 31) << 2;    // column group: 0,4,...,124
  float4 a0 = {0,0,0,0}, a1 = a0, a2 = a0, a3 = a0;
#pragma unroll 4
  for (int k = 0; k < 128; ++k) {
    float4 w = *(const float4*)&Wl[k * 128 + dg];
    float x0 = Xl[(rq + 0) * 128 + k];
    float x1 = Xl[(rq + 1) * 128 + k];
    float x2 = Xl[(rq + 2) * 128 + k];
    float x3 = Xl[(rq + 3) * 128 + k];
    a0.x = fmaf(x0, w.x, a0.x); a0.y = fmaf(x0, w.y, a0.y);
    a0.z = fmaf(x0, w.z, a0.z); a0.w = fmaf(x0, w.w, a0.w);
    a1.x = fmaf(x1, w.x, a1.x); a1.y = fmaf(x1, w.y, a1.y);
    a1.z = fmaf(x1, w.z, a1.z); a1.w = fmaf(x1, w.w, a1.w);
    a2.x = fmaf(x2, w.x, a2.x); a2.y = fmaf(x2, w.y, a2.y);
    a2.z = fmaf(x2, w.z, a2.z); a2.w = fmaf(x2, w.w, a2.w);
    a3.x = fmaf(x3, w.x, a3.x); a3.y = fmaf(x3, w.y, a3.y);
    a3.z = fmaf(x3, w.z, a3.z); a3.w = fmaf(x3, w.w, a3.w);
  }
  if (r0 + rq + 0 < rows) *(float4*)&Y[(size_t)(r0 + rq + 0) * DIM + dg] = a0;
  if (r0 + rq + 1 < rows) *(float4*)&Y[(size_t)(r0 + rq + 1) * DIM + dg] = a1;
  if (r0 + rq + 2 < rows) *(float4*)&Y[(size_t)(r0 + rq + 2) * DIM + dg] = a2;
  if (r0 + rq + 3 < rows) *(float4*)&Y[(size_t)(r0 + rq + 3) * DIM + dg] = a3;
}

// ---------------------------------------------------------------------------
// out[row] = dot(X[row,:], a[0:128]) — one wave per row
// ---------------------------------------------------------------------------
__global__ __launch_bounds__(256) void rowdot_kernel(
    const float* __restrict__ X, const float* __restrict__ a,
    float* __restrict__ out, int rows)
{
  int w = blockIdx.x * (blockDim.x >> 6) + (threadIdx.x >> 6);
  int lane = threadIdx.x & 63;
  if (w >= rows) return;
  const float* row = X + (size_t)w * DIM;
  float v = row[lane] * a[lane] + row[lane + 64] * a[lane + 64];
#pragma unroll
  for (int d = 32; d > 0; d >>= 1) v += __shfl_down(v, d, 64);
  if (lane == 0) out[w] = v;
}

// ---------------------------------------------------------------------------
// Histogram of edge/node incidence + weighted node degree
// ---------------------------------------------------------------------------
__global__ void hist_kernel(const int* __restrict__ node_idx,
                            const int* __restrict__ edge_idx,
                            const float* __restrict__ hw,
                            int* __restrict__ ncnt, int* __restrict__ ecnt,
                            float* __restrict__ Ddeg, int nnz)
{
  int j = blockIdx.x * blockDim.x + threadIdx.x;
  if (j >= nnz) return;
  int e = edge_idx[j], n = node_idx[j];
  atomicAdd(&ecnt[e], 1);
  atomicAdd(&ncnt[n], 1);
  atomicAdd(&Ddeg[n], hw[e]);
}

// ---------------------------------------------------------------------------
// Single-block exclusive scan: off[0..nbins] from cnt[0..nbins-1]
// ---------------------------------------------------------------------------
__global__ __launch_bounds__(1024) void scan_kernel(
    const int* __restrict__ cnt, int* __restrict__ off, int nbins)
{
  __shared__ int warp_sums[16];
  __shared__ int carry_s;
  int tid = threadIdx.x;
  int lane = tid & 63, wid = tid >> 6;
  if (tid == 0) carry_s = 0;
  __syncthreads();
  for (int base = 0; base <= nbins; base += 1024) {
    int i = base + tid;
    int x = (i < nbins) ? cnt[i] : 0;
    int v = x;
#pragma unroll
    for (int d = 1; d < 64; d <<= 1) {
      int y = __shfl_up(v, d, 64);
      if (lane >= d) v += y;
    }
    if (lane == 63) warp_sums[wid] = v;
    __syncthreads();
    if (wid == 0 && lane < 16) {
      int s = warp_sums[lane];
#pragma unroll
      for (int d = 1; d < 16; d <<= 1) {
        int y = __shfl_up(s, d, 16);
        if (lane >= d) s += y;
      }
      warp_sums[lane] = s;
    }
    __syncthreads();
    int pre = carry_s + (wid > 0 ? warp_sums[wid - 1] : 0);
    int incl = pre + v;
    if (i <= nbins) off[i] = incl - x;
    __syncthreads();
    if (tid == 1023) carry_s = incl;
    __syncthreads();
  }
}

// ---------------------------------------------------------------------------
// cursors + inverse degrees
// ---------------------------------------------------------------------------
__global__ void prep_kernel(const int* __restrict__ eoff, const int* __restrict__ noff,
                            int* __restrict__ ecur, int* __restrict__ ncur,
                            const int* __restrict__ ecnt,
                            float* __restrict__ Ddeg_Dinv, float* __restrict__ Binv,
                            int N_, int M_)
{
  int i = blockIdx.x * blockDim.x + threadIdx.x;
  if (i < M_) {
    ecur[i] = eoff[i];
    int c = ecnt[i];
    Binv[i] = c > 0 ? 1.0f / (float)c : 0.0f;
  }
  if (i < N_) {
    ncur[i] = noff[i];
    float d = Ddeg_Dinv[i];
    Ddeg_Dinv[i] = d > 0.0f ? 1.0f / d : 0.0f;
  }
}

// ---------------------------------------------------------------------------
// CSR scatter (both orderings)
// ---------------------------------------------------------------------------
__global__ void scatter_kernel(const int* __restrict__ node_idx,
                               const int* __restrict__ edge_idx,
                               int* __restrict__ ecur, int* __restrict__ ncur,
                               int* __restrict__ eperm, int* __restrict__ nperm, int nnz)
{
  int j = blockIdx.x * blockDim.x + threadIdx.x;
  if (j >= nnz) return;
  int e = edge_idx[j], n = node_idx[j];
  int p = atomicAdd(&ecur[e], 1);
  eperm[p] = j;
  int q = atomicAdd(&ncur[n], 1);
  nperm[q] = j;
}

// ---------------------------------------------------------------------------
// per-incidence attention logit with leaky relu
// ---------------------------------------------------------------------------
__global__ void logit_kernel(const int* __restrict__ node_idx,
                             const int* __restrict__ edge_idx,
                             const float* __restrict__ s_n, const float* __restrict__ s_e,
                             float* __restrict__ alp, int nnz)
{
  int j = blockIdx.x * blockDim.x + threadIdx.x;
  if (j >= nnz) return;
  float x = s_n[node_idx[j]] + s_e[edge_idx[j]];
  alp[j] = x >= 0.0f ? x : NEG_SLOPE * x;
}

// ---------------------------------------------------------------------------
// segment softmax grouped by node — one thread per node, in-place on alp
// ---------------------------------------------------------------------------
__global__ void softmax_kernel(const int* __restrict__ noff, const int* __restrict__ nperm,
                               float* __restrict__ alp, int N_)
{
  int n = blockIdx.x * blockDim.x + threadIdx.x;
  if (n >= N_) return;
  int s = noff[n], e = noff[n + 1];
  if (s == e) return;
  float m = -INFINITY;
  for (int t = s; t < e; ++t) m = fmaxf(m, alp[nperm[t]]);
  float den = 0.0f;
  for (int t = s; t < e; ++t) {
    int j = nperm[t];
    float ex = __expf(alp[j] - m);
    alp[j] = ex;
    den += ex;
  }
  float sc = 1.0f / (den + 1e-16f);
  for (int t = s; t < e; ++t) alp[nperm[t]] *= sc;
}

// ---------------------------------------------------------------------------
// msg1: edge_out[e,:] = sum_{j in edge e} (alpha[j] * Binv[e]) * xt[node[j],:]
// one wave per edge, float2 per lane
// ---------------------------------------------------------------------------
__global__ __launch_bounds__(256) void msg1_kernel(
    const int* __restrict__ eoff, const int* __restrict__ eperm,
    const int* __restrict__ node_idx, const float* __restrict__ alp,
    const float* __restrict__ Binv, const float* __restrict__ xt,
    float* __restrict__ edge_out, int M_)
{
  int e = blockIdx.x * (blockDim.x >> 6) + (threadIdx.x >> 6);
  int lane = threadIdx.x & 63;
  if (e >= M_) return;
  int s = eoff[e], t1 = eoff[e + 1];
  float binv = Binv[e];
  float2 acc = {0.0f, 0.0f};
  for (int t = s; t < t1; ++t) {
    int j = eperm[t];
    float c = alp[j] * binv;
    int nd = node_idx[j];
    float2 v = ((const float2*)(xt + (size_t)nd * DIM))[lane];
    acc.x = fmaf(c, v.x, acc.x);
    acc.y = fmaf(c, v.y, acc.y);
  }
  ((float2*)(edge_out + (size_t)e * DIM))[lane] = acc;
}

// ---------------------------------------------------------------------------
// msg2 fused with residual + accumulation:
//   o[n,:]   = Dinv[n] * sum_{j at n} alpha[j] * edge_out[edge[j],:] + bias
//   cur[n,:] += o ; dout[n,:] += cur[n,:]
// one wave per node
// ---------------------------------------------------------------------------
__global__ __launch_bounds__(256) void msg2_kernel(
    const int* __restrict__ noff, const int* __restrict__ nperm,
    const int* __restrict__ edge_idx, const float* __restrict__ alp,
    const float* __restrict__ Dinv, const float* __restrict__ edge_out,
    const float* __restrict__ bias, float* __restrict__ cur,
    float* __restrict__ dout, int N_)
{
  int n = blockIdx.x * (blockDim.x >> 6) + (threadIdx.x >> 6);
  int lane = threadIdx.x & 63;
  if (n >= N_) return;
  int s = noff[n], t1 = noff[n + 1];
  float2 acc = {0.0f, 0.0f};
  for (int t = s; t < t1; ++t) {
    int j = nperm[t];
    float c = alp[j];
    int e = edge_idx[j];
    float2 v = ((const float2*)(edge_out + (size_t)e * DIM))[lane];
    acc.x = fmaf(c, v.x, acc.x);
    acc.y = fmaf(c, v.y, acc.y);
  }
  float dinv = Dinv[n];
  float2 b = ((const float2*)bias)[lane];
  size_t idx = (size_t)n * DIM + lane * 2;
  float cx = cur[idx], cy = cur[idx + 1];
  cx += acc.x * dinv + b.x;
  cy += acc.y * dinv + b.y;
  cur[idx] = cx; cur[idx + 1] = cy;
  dout[idx] += cx; dout[idx + 1] += cy;
}

// ---------------------------------------------------------------------------
// init: cur = dout = pois ; final: dout *= 0.25
// ---------------------------------------------------------------------------
__global__ void initcopy_kernel(const float4* __restrict__ p,
                                float4* __restrict__ cur, float4* __restrict__ dout,
                                int n4)
{
  int i = blockIdx.x * blockDim.x + threadIdx.x;
  if (i >= n4) return;
  float4 v = p[i];
  cur[i] = v;
  dout[i] = v;
}

__global__ void scale_kernel(float4* __restrict__ dout, int n4)
{
  int i = blockIdx.x * blockDim.x + threadIdx.x;
  if (i >= n4) return;
  float4 v = dout[i];
  v.x *= 0.25f; v.y *= 0.25f; v.z *= 0.25f; v.w *= 0.25f;
  dout[i] = v;
}

// ---------------------------------------------------------------------------

static inline int cdiv(int a, int b) { return (a + b - 1) / b; }

extern "C" void kernel_launch(void* const* d_in, const int* in_sizes, int n_in,
                              void* d_out, int out_size, void* d_ws, size_t ws_size,
                              hipStream_t stream)
{
  const float* pois = (const float*)d_in[0];
  const float* traj = (const float*)d_in[1];
  const float* hw   = (const float*)d_in[2];
  const int* node_idx = (const int*)d_in[3];
  const int* edge_idx = (const int*)d_in[4];
  const float* W    = (const float*)d_in[5];
  const float* att  = (const float*)d_in[6];
  const float* bias = (const float*)d_in[7];
  float* dout = (float*)d_out;

  const int N   = in_sizes[0] / DIM;
  const int M   = in_sizes[2];
  const int NNZ = in_sizes[3];

  char* p = (char*)d_ws;
  auto alloc = [&](size_t bytes) -> void* {
    void* r = (void*)p;
    p += (bytes + 255) & ~(size_t)255;
    return r;
  };
  float* et  = (float*)alloc((size_t)M * DIM * 4);
  float* xt  = (float*)alloc((size_t)N * DIM * 4);
  float* cur = (float*)alloc((size_t)N * DIM * 4);
  float* edge_out = (float*)alloc((size_t)M * DIM * 4);
  float* alp = (float*)alloc((size_t)NNZ * 4);
  float* s_e = (float*)alloc((size_t)M * 4);
  float* s_n = (float*)alloc((size_t)N * 4);
  float* Dinv = (float*)alloc((size_t)N * 4);   // Ddeg then inverted in-place
  float* Binv = (float*)alloc((size_t)M * 4);
  int* ecnt = (int*)alloc((size_t)M * 4);
  int* ncnt = (int*)alloc((size_t)N * 4);
  int* eoff = (int*)alloc((size_t)(M + 1) * 4);
  int* noff = (int*)alloc((size_t)(N + 1) * 4);
  int* ecur = (int*)alloc((size_t)M * 4);
  int* ncur = (int*)alloc((size_t)N * 4);
  int* eperm = (int*)alloc((size_t)NNZ * 4);
  int* nperm = (int*)alloc((size_t)NNZ * 4);
  (void)ws_size;

  // ---- incidence structure (layer-invariant) ----
  hipMemsetAsync(ecnt, 0, (size_t)M * 4, stream);
  hipMemsetAsync(ncnt, 0, (size_t)N * 4, stream);
  hipMemsetAsync(Dinv, 0, (size_t)N * 4, stream);
  hist_kernel<<<cdiv(NNZ, 256), 256, 0, stream>>>(node_idx, edge_idx, hw, ncnt, ecnt, Dinv, NNZ);
  scan_kernel<<<1, 1024, 0, stream>>>(ecnt, eoff, M);
  scan_kernel<<<1, 1024, 0, stream>>>(ncnt, noff, N);
  prep_kernel<<<cdiv(N > M ? N : M, 256), 256, 0, stream>>>(eoff, noff, ecur, ncur, ecnt, Dinv, Binv, N, M);
  scatter_kernel<<<cdiv(NNZ, 256), 256, 0, stream>>>(node_idx, edge_idx, ecur, ncur, eperm, nperm, NNZ);

  // ---- layer-invariant dense work ----
  gemm128_kernel<<<cdiv(M, 32), 256, 0, stream>>>(traj, W, et, M);
  rowdot_kernel<<<cdiv(M, 4), 256, 0, stream>>>(et, att + DIM, s_e, M);

  // ---- init cur / accumulator ----
  int n4 = (N * DIM) / 4;
  initcopy_kernel<<<cdiv(n4, 256), 256, 0, stream>>>((const float4*)pois, (float4*)cur, (float4*)dout, n4);

  // ---- layers ----
  for (int layer = 0; layer < 3; ++layer) {
    gemm128_kernel<<<cdiv(N, 32), 256, 0, stream>>>(cur, W, xt, N);
    rowdot_kernel<<<cdiv(N, 4), 256, 0, stream>>>(xt, att, s_n, N);
    logit_kernel<<<cdiv(NNZ, 256), 256, 0, stream>>>(node_idx, edge_idx, s_n, s_e, alp, NNZ);
    softmax_kernel<<<cdiv(N, 256), 256, 0, stream>>>(noff, nperm, alp, N);
    msg1_kernel<<<cdiv(M, 4), 256, 0, stream>>>(eoff, eperm, node_idx, alp, Binv, xt, edge_out, M);
    msg2_kernel<<<cdiv(N, 4), 256, 0, stream>>>(noff, nperm, edge_idx, alp, Dinv, edge_out, bias, cur, dout, N);
  }

  scale_kernel<<<cdiv(n4, 256), 256, 0, stream>>>((float4*)dout, n4);
}

// Round 2
// 1457.279 us; speedup vs baseline: 1.3919x; 1.3919x over previous
//
#include <hip/hip_runtime.h>
#include <cstdint>
#include <cstddef>

#define DIM 128
#define NEG_SLOPE 0.2f

// ---- bf16 helpers (manual, RNE) -------------------------------------------
__device__ __forceinline__ float bf_lo(uint u) { return __uint_as_float(u << 16); }
__device__ __forceinline__ float bf_hi(uint u) { return __uint_as_float(u & 0xffff0000u); }
__device__ __forceinline__ uint f2bf(float f) {
  uint u = __float_as_uint(f);
  return (u + 0x7fffu + ((u >> 16) & 1u)) >> 16;
}
__device__ __forceinline__ uint pack_bf2(float lo, float hi) {
  return f2bf(lo) | (f2bf(hi) << 16);
}

// ---------------------------------------------------------------------------
// GEMM: Y_bf16[rows x 128] = X[rows x 128] @ W[128 x 128] (fp32 compute).
// W in LDS; 32 rows/block; 4x4 register tile per thread.
// ---------------------------------------------------------------------------
__global__ __launch_bounds__(256) void gemm128_kernel(
    const float* __restrict__ X, const float* __restrict__ W,
    ushort* __restrict__ Yb, int rows)
{
  __shared__ float Wl[128 * 128];
  __shared__ float Xl[32 * 128];
  int tid = threadIdx.x;
  {
    const float4* W4 = (const float4*)W;
    float4* Wl4 = (float4*)Wl;
#pragma unroll
    for (int i = 0; i < 16; ++i) Wl4[tid + i * 256] = W4[tid + i * 256];
  }
  int r0 = blockIdx.x * 32;
  int nrow = rows - r0; if (nrow > 32) nrow = 32;
  {
    const float4* X4 = (const float4*)(X + (size_t)r0 * DIM);
    float4* Xl4 = (float4*)Xl;
    for (int i = tid; i < nrow * 32; i += 256) Xl4[i] = X4[i];
  }
  __syncthreads();
  int rq = (tid >> 5) << 2;
  int dg = (tid & 31) << 2;
  float4 a0 = {0,0,0,0}, a1 = a0, a2 = a0, a3 = a0;
#pragma unroll 4
  for (int k = 0; k < 128; ++k) {
    float4 w = *(const float4*)&Wl[k * 128 + dg];
    float x0 = Xl[(rq + 0) * 128 + k];
    float x1 = Xl[(rq + 1) * 128 + k];
    float x2 = Xl[(rq + 2) * 128 + k];
    float x3 = Xl[(rq + 3) * 128 + k];
    a0.x = fmaf(x0, w.x, a0.x); a0.y = fmaf(x0, w.y, a0.y);
    a0.z = fmaf(x0, w.z, a0.z); a0.w = fmaf(x0, w.w, a0.w);
    a1.x = fmaf(x1, w.x, a1.x); a1.y = fmaf(x1, w.y, a1.y);
    a1.z = fmaf(x1, w.z, a1.z); a1.w = fmaf(x1, w.w, a1.w);
    a2.x = fmaf(x2, w.x, a2.x); a2.y = fmaf(x2, w.y, a2.y);
    a2.z = fmaf(x2, w.z, a2.z); a2.w = fmaf(x2, w.w, a2.w);
    a3.x = fmaf(x3, w.x, a3.x); a3.y = fmaf(x3, w.y, a3.y);
    a3.z = fmaf(x3, w.z, a3.z); a3.w = fmaf(x3, w.w, a3.w);
  }
  ushort4 h;
#define STORE_BF(acc, r) \
  if (r0 + (r) < rows) { \
    h.x = (ushort)f2bf(acc.x); h.y = (ushort)f2bf(acc.y); \
    h.z = (ushort)f2bf(acc.z); h.w = (ushort)f2bf(acc.w); \
    *(ushort4*)&Yb[(size_t)(r0 + (r)) * DIM + dg] = h; }
  STORE_BF(a0, rq + 0)
  STORE_BF(a1, rq + 1)
  STORE_BF(a2, rq + 2)
  STORE_BF(a3, rq + 3)
#undef STORE_BF
}

// ---------------------------------------------------------------------------
// out[row] = dot(X[row,:], a[0:128]) — one wave per row (fp32)
// ---------------------------------------------------------------------------
__global__ __launch_bounds__(256) void rowdot_kernel(
    const float* __restrict__ X, const float* __restrict__ a,
    float* __restrict__ out, int rows)
{
  int w = blockIdx.x * (blockDim.x >> 6) + (threadIdx.x >> 6);
  int lane = threadIdx.x & 63;
  if (w >= rows) return;
  const float* row = X + (size_t)w * DIM;
  float v = row[lane] * a[lane] + row[lane + 64] * a[lane + 64];
#pragma unroll
  for (int d = 32; d > 0; d >>= 1) v += __shfl_down(v, d, 64);
  if (lane == 0) out[w] = v;
}

// ---------------------------------------------------------------------------
// Histogram + weighted node degree
// ---------------------------------------------------------------------------
__global__ void hist_kernel(const int* __restrict__ node_idx,
                            const int* __restrict__ edge_idx,
                            const float* __restrict__ hw,
                            int* __restrict__ ncnt, int* __restrict__ ecnt,
                            float* __restrict__ Ddeg, int nnz)
{
  int j = blockIdx.x * blockDim.x + threadIdx.x;
  if (j >= nnz) return;
  int e = edge_idx[j], n = node_idx[j];
  atomicAdd(&ecnt[e], 1);
  atomicAdd(&ncnt[n], 1);
  atomicAdd(&Ddeg[n], hw[e]);
}

// ---------------------------------------------------------------------------
// Single-block exclusive scan
// ---------------------------------------------------------------------------
__global__ __launch_bounds__(1024) void scan_kernel(
    const int* __restrict__ cnt, int* __restrict__ off, int nbins)
{
  __shared__ int warp_sums[16];
  __shared__ int carry_s;
  int tid = threadIdx.x;
  int lane = tid & 63, wid = tid >> 6;
  if (tid == 0) carry_s = 0;
  __syncthreads();
  for (int base = 0; base <= nbins; base += 1024) {
    int i = base + tid;
    int x = (i < nbins) ? cnt[i] : 0;
    int v = x;
#pragma unroll
    for (int d = 1; d < 64; d <<= 1) {
      int y = __shfl_up(v, d, 64);
      if (lane >= d) v += y;
    }
    if (lane == 63) warp_sums[wid] = v;
    __syncthreads();
    if (wid == 0 && lane < 16) {
      int s = warp_sums[lane];
#pragma unroll
      for (int d = 1; d < 16; d <<= 1) {
        int y = __shfl_up(s, d, 16);
        if (lane >= d) s += y;
      }
      warp_sums[lane] = s;
    }
    __syncthreads();
    int pre = carry_s + (wid > 0 ? warp_sums[wid - 1] : 0);
    int incl = pre + v;
    if (i <= nbins) off[i] = incl - x;
    __syncthreads();
    if (tid == 1023) carry_s = incl;
    __syncthreads();
  }
}

// ---------------------------------------------------------------------------
// cursors + inverse degrees
// ---------------------------------------------------------------------------
__global__ void prep_kernel(const int* __restrict__ eoff, const int* __restrict__ noff,
                            int* __restrict__ ecur, int* __restrict__ ncur,
                            const int* __restrict__ ecnt,
                            float* __restrict__ Ddeg_Dinv, float* __restrict__ Binv,
                            int N_, int M_)
{
  int i = blockIdx.x * blockDim.x + threadIdx.x;
  if (i < M_) {
    ecur[i] = eoff[i];
    int c = ecnt[i];
    Binv[i] = c > 0 ? 1.0f / (float)c : 0.0f;
  }
  if (i < N_) {
    ncur[i] = noff[i];
    float d = Ddeg_Dinv[i];
    Ddeg_Dinv[i] = d > 0.0f ? 1.0f / d : 0.0f;
  }
}

// ---------------------------------------------------------------------------
// CSR scatters, split to keep active-line footprint inside L2 (write-amp fix).
// Payload-carrying: edge-CSR stores the node id; node-CSR stores the edge id.
// ---------------------------------------------------------------------------
__global__ void scatter_edge_kernel(const int* __restrict__ node_idx,
                                    const int* __restrict__ edge_idx,
                                    int* __restrict__ ecur,
                                    int* __restrict__ nd_e, int nnz)
{
  int j = blockIdx.x * blockDim.x + threadIdx.x;
  if (j >= nnz) return;
  int e = edge_idx[j], n = node_idx[j];
  int p = atomicAdd(&ecur[e], 1);
  nd_e[p] = n;
}

__global__ void scatter_node_kernel(const int* __restrict__ node_idx,
                                    const int* __restrict__ edge_idx,
                                    int* __restrict__ ncur,
                                    int* __restrict__ eidx_n, int nnz)
{
  int j = blockIdx.x * blockDim.x + threadIdx.x;
  if (j >= nnz) return;
  int e = edge_idx[j], n = node_idx[j];
  int q = atomicAdd(&ncur[n], 1);
  eidx_n[q] = e;
}

// ---------------------------------------------------------------------------
// Per-node online softmax stats: node_soft[n] = {s_n, m, 1/(den+1e-16), Dinv}
// One thread per node; single pass over its incidences.
// ---------------------------------------------------------------------------
__global__ void softstat_kernel(const int* __restrict__ noff,
                                const int* __restrict__ eidx_n,
                                const float* __restrict__ s_n,
                                const float* __restrict__ s_e,
                                const float* __restrict__ Dinv,
                                float4* __restrict__ node_soft, int N_)
{
  int n = blockIdx.x * blockDim.x + threadIdx.x;
  if (n >= N_) return;
  int s = noff[n], e1 = noff[n + 1];
  float sn = s_n[n];
  float m = -INFINITY, den = 0.0f;
  for (int t = s; t < e1; ++t) {
    float l = sn + s_e[eidx_n[t]];
    l = l >= 0.0f ? l : NEG_SLOPE * l;
    if (l > m) { den = den * __expf(m - l) + 1.0f; m = l; }
    else den += __expf(l - m);
  }
  if (s == e1) m = 0.0f;
  float4 r;
  r.x = sn; r.y = m; r.z = 1.0f / (den + 1e-16f); r.w = Dinv[n];
  node_soft[n] = r;
}

// ---------------------------------------------------------------------------
// msg1: edge_out_bf16[e,:] = sum_{j in e} alpha_j * Binv[e] * xt_bf16[nd_j,:]
// one wave per edge; alpha recomputed from node_soft (one float4 broadcast).
// ---------------------------------------------------------------------------
__global__ __launch_bounds__(256) void msg1_kernel(
    const int* __restrict__ eoff, const int* __restrict__ nd_e,
    const float4* __restrict__ node_soft, const float* __restrict__ s_e,
    const float* __restrict__ Binv, const ushort* __restrict__ xt,
    uint* __restrict__ eo, int M_)
{
  int e = blockIdx.x * (blockDim.x >> 6) + (threadIdx.x >> 6);
  int lane = threadIdx.x & 63;
  if (e >= M_) return;
  int s = eoff[e], t1 = eoff[e + 1];
  float binv = Binv[e];
  float se = s_e[e];
  float2 acc = {0.0f, 0.0f};
  for (int t = s; t < t1; ++t) {
    int nd = nd_e[t];
    float4 ns = node_soft[nd];
    float l = ns.x + se;
    l = l >= 0.0f ? l : NEG_SLOPE * l;
    float c = __expf(l - ns.y) * ns.z * binv;
    uint u = *(const uint*)&xt[(size_t)nd * DIM + lane * 2];
    acc.x = fmaf(c, bf_lo(u), acc.x);
    acc.y = fmaf(c, bf_hi(u), acc.y);
  }
  eo[(size_t)e * (DIM / 2) + lane] = pack_bf2(acc.x, acc.y);
}

// ---------------------------------------------------------------------------
// msg2 fused with residual + stack accumulation. One wave per node.
//   out = (den_inv*Dinv) * sum_j ex_j * edge_out[e_j,:] + bias
//   cur += out ; dout += cur
// ---------------------------------------------------------------------------
__global__ __launch_bounds__(256) void msg2_kernel(
    const int* __restrict__ noff, const int* __restrict__ eidx_n,
    const float4* __restrict__ node_soft, const float* __restrict__ s_e,
    const uint* __restrict__ eo, const float* __restrict__ bias,
    float* __restrict__ cur, float* __restrict__ dout, int N_)
{
  int n = blockIdx.x * (blockDim.x >> 6) + (threadIdx.x >> 6);
  int lane = threadIdx.x & 63;
  if (n >= N_) return;
  int s = noff[n], t1 = noff[n + 1];
  float4 ns = node_soft[n];
  float2 acc = {0.0f, 0.0f};
  for (int t = s; t < t1; ++t) {
    int e = eidx_n[t];
    float l = ns.x + s_e[e];
    l = l >= 0.0f ? l : NEG_SLOPE * l;
    float ex = __expf(l - ns.y);
    uint u = eo[(size_t)e * (DIM / 2) + lane];
    acc.x = fmaf(ex, bf_lo(u), acc.x);
    acc.y = fmaf(ex, bf_hi(u), acc.y);
  }
  float sc = ns.z * ns.w;
  float2 b = ((const float2*)bias)[lane];
  size_t idx = (size_t)n * DIM + lane * 2;
  float cx = cur[idx], cy = cur[idx + 1];
  cx += acc.x * sc + b.x;
  cy += acc.y * sc + b.y;
  cur[idx] = cx; cur[idx + 1] = cy;
  dout[idx] += cx; dout[idx + 1] += cy;
}

// ---------------------------------------------------------------------------
__global__ void initcopy_kernel(const float4* __restrict__ p,
                                float4* __restrict__ cur, float4* __restrict__ dout,
                                int n4)
{
  int i = blockIdx.x * blockDim.x + threadIdx.x;
  if (i >= n4) return;
  float4 v = p[i];
  cur[i] = v;
  dout[i] = v;
}

__global__ void scale_kernel(float4* __restrict__ dout, int n4)
{
  int i = blockIdx.x * blockDim.x + threadIdx.x;
  if (i >= n4) return;
  float4 v = dout[i];
  v.x *= 0.25f; v.y *= 0.25f; v.z *= 0.25f; v.w *= 0.25f;
  dout[i] = v;
}

// ---------------------------------------------------------------------------
static inline int cdiv(int a, int b) { return (a + b - 1) / b; }

extern "C" void kernel_launch(void* const* d_in, const int* in_sizes, int n_in,
                              void* d_out, int out_size, void* d_ws, size_t ws_size,
                              hipStream_t stream)
{
  const float* pois = (const float*)d_in[0];
  const float* traj = (const float*)d_in[1];
  const float* hw   = (const float*)d_in[2];
  const int* node_idx = (const int*)d_in[3];
  const int* edge_idx = (const int*)d_in[4];
  const float* W    = (const float*)d_in[5];
  const float* att  = (const float*)d_in[6];
  const float* bias = (const float*)d_in[7];
  float* dout = (float*)d_out;

  const int N   = in_sizes[0] / DIM;
  const int M   = in_sizes[2];
  const int NNZ = in_sizes[3];

  char* p = (char*)d_ws;
  auto alloc = [&](size_t bytes) -> void* {
    void* r = (void*)p;
    p += (bytes + 255) & ~(size_t)255;
    return r;
  };
  ushort* xt_bf = (ushort*)alloc((size_t)N * DIM * 2);      // 25.6 MB
  uint*   eo_bf = (uint*)alloc((size_t)M * (DIM / 2) * 4);  //  5.1 MB
  float*  cur   = (float*)alloc((size_t)N * DIM * 4);       // 51.2 MB
  float4* node_soft = (float4*)alloc((size_t)N * 16);       //  1.6 MB
  float*  s_e  = (float*)alloc((size_t)M * 4);
  float*  s_n  = (float*)alloc((size_t)N * 4);
  float*  Dinv = (float*)alloc((size_t)N * 4);              // Ddeg then inverted
  float*  Binv = (float*)alloc((size_t)M * 4);
  float*  wv1  = (float*)alloc(DIM * 4);
  float*  wv2  = (float*)alloc(DIM * 4);
  int* ecnt = (int*)alloc((size_t)M * 4);
  int* ncnt = (int*)alloc((size_t)N * 4);
  int* eoff = (int*)alloc((size_t)(M + 1) * 4);
  int* noff = (int*)alloc((size_t)(N + 1) * 4);
  int* ecur = (int*)alloc((size_t)M * 4);
  int* ncur = (int*)alloc((size_t)N * 4);
  int* nd_e   = (int*)alloc((size_t)NNZ * 4);
  int* eidx_n = (int*)alloc((size_t)NNZ * 4);
  (void)ws_size;

  // ---- incidence structure (layer-invariant) ----
  hipMemsetAsync(ecnt, 0, (size_t)M * 4, stream);
  hipMemsetAsync(ncnt, 0, (size_t)N * 4, stream);
  hipMemsetAsync(Dinv, 0, (size_t)N * 4, stream);
  hist_kernel<<<cdiv(NNZ, 256), 256, 0, stream>>>(node_idx, edge_idx, hw, ncnt, ecnt, Dinv, NNZ);
  scan_kernel<<<1, 1024, 0, stream>>>(ecnt, eoff, M);
  scan_kernel<<<1, 1024, 0, stream>>>(ncnt, noff, N);
  prep_kernel<<<cdiv(N > M ? N : M, 256), 256, 0, stream>>>(eoff, noff, ecur, ncur, ecnt, Dinv, Binv, N, M);
  scatter_edge_kernel<<<cdiv(NNZ, 256), 256, 0, stream>>>(node_idx, edge_idx, ecur, nd_e, NNZ);
  scatter_node_kernel<<<cdiv(NNZ, 256), 256, 0, stream>>>(node_idx, edge_idx, ncur, eidx_n, NNZ);

  // ---- layer-invariant dense work: s_e = traj @ (W @ att2) ----
  rowdot_kernel<<<cdiv(DIM, 4), 256, 0, stream>>>(W, att, wv1, DIM);        // wv1 = W @ att[:D]
  rowdot_kernel<<<cdiv(DIM, 4), 256, 0, stream>>>(W, att + DIM, wv2, DIM);  // wv2 = W @ att[D:]
  rowdot_kernel<<<cdiv(M, 4), 256, 0, stream>>>(traj, wv2, s_e, M);

  // ---- init cur / accumulator ----
  int n4 = (N * DIM) / 4;
  initcopy_kernel<<<cdiv(n4, 256), 256, 0, stream>>>((const float4*)pois, (float4*)cur, (float4*)dout, n4);

  // ---- layers ----
  for (int layer = 0; layer < 3; ++layer) {
    gemm128_kernel<<<cdiv(N, 32), 256, 0, stream>>>(cur, W, xt_bf, N);
    rowdot_kernel<<<cdiv(N, 4), 256, 0, stream>>>(cur, wv1, s_n, N);  // s_n = cur @ (W@att1)
    softstat_kernel<<<cdiv(N, 256), 256, 0, stream>>>(noff, eidx_n, s_n, s_e, Dinv, node_soft, N);
    msg1_kernel<<<cdiv(M, 4), 256, 0, stream>>>(eoff, nd_e, node_soft, s_e, Binv, xt_bf, eo_bf, M);
    msg2_kernel<<<cdiv(N, 4), 256, 0, stream>>>(noff, eidx_n, node_soft, s_e, eo_bf, bias, cur, dout, N);
  }

  scale_kernel<<<cdiv(n4, 256), 256, 0, stream>>>((float4*)dout, n4);
}

// Round 3
// 1202.299 us; speedup vs baseline: 1.6871x; 1.2121x over previous
//
#include <hip/hip_runtime.h>
#include <cstdint>
#include <cstddef>

#define DIM 128
#define NEG_SLOPE 0.2f

// ---- bf16 helpers (manual, RNE) -------------------------------------------
__device__ __forceinline__ float bf_lo(uint u) { return __uint_as_float(u << 16); }
__device__ __forceinline__ float bf_hi(uint u) { return __uint_as_float(u & 0xffff0000u); }
__device__ __forceinline__ uint f2bf(float f) {
  uint u = __float_as_uint(f);
  return (u + 0x7fffu + ((u >> 16) & 1u)) >> 16;
}
__device__ __forceinline__ uint pack_bf2(float lo, float hi) {
  return f2bf(lo) | (f2bf(hi) << 16);
}

// ---------------------------------------------------------------------------
// GEMM: Y_bf16[rows x 128] = X[rows x 128] @ W[128 x 128] (fp32 compute),
// fused epilogue: s_n[row] = dot(Y_fp32[row,:], att[0:128]).
// W in LDS; 32 rows/block; 4x4 register tile per thread.
// ---------------------------------------------------------------------------
__global__ __launch_bounds__(256) void gemm128_kernel(
    const float* __restrict__ X, const float* __restrict__ W,
    const float* __restrict__ att, ushort* __restrict__ Yb,
    float* __restrict__ s_n, int rows)
{
  __shared__ float Wl[128 * 128];
  __shared__ float Xl[32 * 128];
  int tid = threadIdx.x;
  {
    const float4* W4 = (const float4*)W;
    float4* Wl4 = (float4*)Wl;
#pragma unroll
    for (int i = 0; i < 16; ++i) Wl4[tid + i * 256] = W4[tid + i * 256];
  }
  int r0 = blockIdx.x * 32;
  int nrow = rows - r0; if (nrow > 32) nrow = 32;
  {
    const float4* X4 = (const float4*)(X + (size_t)r0 * DIM);
    float4* Xl4 = (float4*)Xl;
    for (int i = tid; i < nrow * 32; i += 256) Xl4[i] = X4[i];
  }
  __syncthreads();
  int rq = (tid >> 5) << 2;
  int dg = (tid & 31) << 2;
  float4 a0 = {0,0,0,0}, a1 = a0, a2 = a0, a3 = a0;
#pragma unroll 4
  for (int k = 0; k < 128; ++k) {
    float4 w = *(const float4*)&Wl[k * 128 + dg];
    float x0 = Xl[(rq + 0) * 128 + k];
    float x1 = Xl[(rq + 1) * 128 + k];
    float x2 = Xl[(rq + 2) * 128 + k];
    float x3 = Xl[(rq + 3) * 128 + k];
    a0.x = fmaf(x0, w.x, a0.x); a0.y = fmaf(x0, w.y, a0.y);
    a0.z = fmaf(x0, w.z, a0.z); a0.w = fmaf(x0, w.w, a0.w);
    a1.x = fmaf(x1, w.x, a1.x); a1.y = fmaf(x1, w.y, a1.y);
    a1.z = fmaf(x1, w.z, a1.z); a1.w = fmaf(x1, w.w, a1.w);
    a2.x = fmaf(x2, w.x, a2.x); a2.y = fmaf(x2, w.y, a2.y);
    a2.z = fmaf(x2, w.z, a2.z); a2.w = fmaf(x2, w.w, a2.w);
    a3.x = fmaf(x3, w.x, a3.x); a3.y = fmaf(x3, w.y, a3.y);
    a3.z = fmaf(x3, w.z, a3.z); a3.w = fmaf(x3, w.w, a3.w);
  }
  ushort4 h;
#define STORE_BF(acc, r) \
  if (r0 + (r) < rows) { \
    h.x = (ushort)f2bf(acc.x); h.y = (ushort)f2bf(acc.y); \
    h.z = (ushort)f2bf(acc.z); h.w = (ushort)f2bf(acc.w); \
    *(ushort4*)&Yb[(size_t)(r0 + (r)) * DIM + dg] = h; }
  STORE_BF(a0, rq + 0)
  STORE_BF(a1, rq + 1)
  STORE_BF(a2, rq + 2)
  STORE_BF(a3, rq + 3)
#undef STORE_BF
  // fused s_n epilogue: reduce tile * att across the 32 lanes sharing a row quad
  float4 av = *(const float4*)&att[dg];
  float s0 = a0.x*av.x + a0.y*av.y + a0.z*av.z + a0.w*av.w;
  float s1 = a1.x*av.x + a1.y*av.y + a1.z*av.z + a1.w*av.w;
  float s2 = a2.x*av.x + a2.y*av.y + a2.z*av.z + a2.w*av.w;
  float s3 = a3.x*av.x + a3.y*av.y + a3.z*av.z + a3.w*av.w;
#pragma unroll
  for (int m = 16; m >= 1; m >>= 1) {
    s0 += __shfl_xor(s0, m, 64);
    s1 += __shfl_xor(s1, m, 64);
    s2 += __shfl_xor(s2, m, 64);
    s3 += __shfl_xor(s3, m, 64);
  }
  if ((tid & 31) == 0) {
    if (r0 + rq + 0 < rows) s_n[r0 + rq + 0] = s0;
    if (r0 + rq + 1 < rows) s_n[r0 + rq + 1] = s1;
    if (r0 + rq + 2 < rows) s_n[r0 + rq + 2] = s2;
    if (r0 + rq + 3 < rows) s_n[r0 + rq + 3] = s3;
  }
}

// ---------------------------------------------------------------------------
// out[row] = dot(X[row,:], a[0:128]) — one wave per row (fp32)
// ---------------------------------------------------------------------------
__global__ __launch_bounds__(256) void rowdot_kernel(
    const float* __restrict__ X, const float* __restrict__ a,
    float* __restrict__ out, int rows)
{
  int w = blockIdx.x * (blockDim.x >> 6) + (threadIdx.x >> 6);
  int lane = threadIdx.x & 63;
  if (w >= rows) return;
  const float* row = X + (size_t)w * DIM;
  float v = row[lane] * a[lane] + row[lane + 64] * a[lane + 64];
#pragma unroll
  for (int d = 32; d > 0; d >>= 1) v += __shfl_down(v, d, 64);
  if (lane == 0) out[w] = v;
}

// ---------------------------------------------------------------------------
// Rank-fused histogram: counts AND within-segment ranks in one pass.
// ---------------------------------------------------------------------------
__global__ void hist_rank_kernel(const int* __restrict__ node_idx,
                                 const int* __restrict__ edge_idx,
                                 int* __restrict__ ncnt, int* __restrict__ ecnt,
                                 int* __restrict__ r_n, int* __restrict__ r_e,
                                 int nnz)
{
  int j = blockIdx.x * blockDim.x + threadIdx.x;
  if (j >= nnz) return;
  r_e[j] = atomicAdd(&ecnt[edge_idx[j]], 1);
  r_n[j] = atomicAdd(&ncnt[node_idx[j]], 1);
}

// ---------------------------------------------------------------------------
// Two-level exclusive scan: block pass (4096/block) -> partials -> add
// ---------------------------------------------------------------------------
__global__ __launch_bounds__(1024) void scan_block_kernel(
    const int* __restrict__ cnt, int* __restrict__ off,
    int* __restrict__ partials, int nbins)
{
  __shared__ int ws[16];
  int tid = threadIdx.x, lane = tid & 63, wid = tid >> 6;
  int base = blockIdx.x * 4096 + tid * 4;
  int x0 = base + 0 < nbins ? cnt[base + 0] : 0;
  int x1 = base + 1 < nbins ? cnt[base + 1] : 0;
  int x2 = base + 2 < nbins ? cnt[base + 2] : 0;
  int x3 = base + 3 < nbins ? cnt[base + 3] : 0;
  int t = x0 + x1 + x2 + x3;
  int v = t;
#pragma unroll
  for (int d = 1; d < 64; d <<= 1) {
    int y = __shfl_up(v, d, 64);
    if (lane >= d) v += y;
  }
  if (lane == 63) ws[wid] = v;
  __syncthreads();
  if (tid < 16) {
    int s = ws[tid];
#pragma unroll
    for (int d = 1; d < 16; d <<= 1) {
      int y = __shfl_up(s, d, 16);
      if (tid >= d) s += y;
    }
    ws[tid] = s;
  }
  __syncthreads();
  int pre = (wid > 0 ? ws[wid - 1] : 0) + (v - t);
  if (base + 0 < nbins) off[base + 0] = pre;
  if (base + 1 < nbins) off[base + 1] = pre + x0;
  if (base + 2 < nbins) off[base + 2] = pre + x0 + x1;
  if (base + 3 < nbins) off[base + 3] = pre + x0 + x1 + x2;
  if (tid == 0) partials[blockIdx.x] = ws[15];
}

__global__ __launch_bounds__(64) void scan_partials_kernel(
    int* __restrict__ partials, int nb)  // nb <= 64
{
  int lane = threadIdx.x;
  int t = lane < nb ? partials[lane] : 0;
  int v = t;
#pragma unroll
  for (int d = 1; d < 64; d <<= 1) {
    int y = __shfl_up(v, d, 64);
    if (lane >= d) v += y;
  }
  if (lane < nb) partials[lane] = v - t;
  if (lane == 63) partials[nb] = v;  // grand total
}

__global__ void add_off_kernel(int* __restrict__ off,
                               const int* __restrict__ partials,
                               int nbins, int nb)
{
  int i = blockIdx.x * blockDim.x + threadIdx.x;
  if (i < nbins) off[i] += partials[i >> 12];
  if (i == 0) off[nbins] = partials[nb];
}

// ---------------------------------------------------------------------------
// Atomic-free CSR scatters using precomputed ranks (payload-carrying)
// ---------------------------------------------------------------------------
__global__ void scatter_edge_kernel(const int* __restrict__ node_idx,
                                    const int* __restrict__ edge_idx,
                                    const int* __restrict__ r_e,
                                    const int* __restrict__ eoff,
                                    int* __restrict__ nd_e, int nnz)
{
  int j = blockIdx.x * blockDim.x + threadIdx.x;
  if (j >= nnz) return;
  int e = edge_idx[j];
  nd_e[eoff[e] + r_e[j]] = node_idx[j];
}

__global__ void scatter_node_kernel(const int* __restrict__ node_idx,
                                    const int* __restrict__ edge_idx,
                                    const int* __restrict__ r_n,
                                    const int* __restrict__ noff,
                                    int* __restrict__ eidx_n, int nnz)
{
  int j = blockIdx.x * blockDim.x + threadIdx.x;
  if (j >= nnz) return;
  int n = node_idx[j];
  eidx_n[noff[n] + r_n[j]] = edge_idx[j];
}

// ---------------------------------------------------------------------------
// Dinv[n] = 1 / sum_{e at n} hw[e]  (from node-CSR, no atomics)
// ---------------------------------------------------------------------------
__global__ void ddeg_kernel(const int* __restrict__ noff,
                            const int* __restrict__ eidx_n,
                            const float* __restrict__ hw,
                            float* __restrict__ Dinv, int N_)
{
  int n = blockIdx.x * blockDim.x + threadIdx.x;
  if (n >= N_) return;
  int s = noff[n], e1 = noff[n + 1];
  float d = 0.0f;
  for (int t = s; t < e1; ++t) d += hw[eidx_n[t]];
  Dinv[n] = d > 0.0f ? 1.0f / d : 0.0f;
}

// ---------------------------------------------------------------------------
// Per-node online softmax stats: node_soft[n] = {s_n, m, 1/(den+1e-16), Dinv}
// ---------------------------------------------------------------------------
__global__ void softstat_kernel(const int* __restrict__ noff,
                                const int* __restrict__ eidx_n,
                                const float* __restrict__ s_n,
                                const float* __restrict__ s_e,
                                const float* __restrict__ Dinv,
                                float4* __restrict__ node_soft, int N_)
{
  int n = blockIdx.x * blockDim.x + threadIdx.x;
  if (n >= N_) return;
  int s = noff[n], e1 = noff[n + 1];
  float sn = s_n[n];
  float m = -INFINITY, den = 0.0f;
  for (int t = s; t < e1; ++t) {
    float l = sn + s_e[eidx_n[t]];
    l = l >= 0.0f ? l : NEG_SLOPE * l;
    if (l > m) { den = den * __expf(m - l) + 1.0f; m = l; }
    else den += __expf(l - m);
  }
  if (s == e1) m = 0.0f;
  float4 r;
  r.x = sn; r.y = m; r.z = 1.0f / (den + 1e-16f); r.w = Dinv[n];
  node_soft[n] = r;
}

// ---------------------------------------------------------------------------
// msg1: eo_bf16[e,:] = sum_{j in e} alpha_j / |e| * xt_bf16[nd_j,:]
// one wave per edge; alpha recomputed from node_soft broadcast.
// ---------------------------------------------------------------------------
__global__ __launch_bounds__(256) void msg1_kernel(
    const int* __restrict__ eoff, const int* __restrict__ nd_e,
    const float4* __restrict__ node_soft, const float* __restrict__ s_e,
    const ushort* __restrict__ xt, uint* __restrict__ eo, int M_)
{
  int e = blockIdx.x * (blockDim.x >> 6) + (threadIdx.x >> 6);
  int lane = threadIdx.x & 63;
  if (e >= M_) return;
  int s = eoff[e], t1 = eoff[e + 1];
  float binv = (t1 > s) ? 1.0f / (float)(t1 - s) : 0.0f;
  float se = s_e[e];
  float2 acc = {0.0f, 0.0f};
  for (int t = s; t < t1; ++t) {
    int nd = nd_e[t];
    float4 ns = node_soft[nd];
    float l = ns.x + se;
    l = l >= 0.0f ? l : NEG_SLOPE * l;
    float c = __expf(l - ns.y) * ns.z * binv;
    uint u = *(const uint*)&xt[(size_t)nd * DIM + lane * 2];
    acc.x = fmaf(c, bf_lo(u), acc.x);
    acc.y = fmaf(c, bf_hi(u), acc.y);
  }
  eo[(size_t)e * (DIM / 2) + lane] = pack_bf2(acc.x, acc.y);
}

// ---------------------------------------------------------------------------
// msg2 fused with residual + stack accumulation. One wave per node.
// ---------------------------------------------------------------------------
__global__ __launch_bounds__(256) void msg2_kernel(
    const int* __restrict__ noff, const int* __restrict__ eidx_n,
    const float4* __restrict__ node_soft, const float* __restrict__ s_e,
    const uint* __restrict__ eo, const float* __restrict__ bias,
    float* __restrict__ cur, float* __restrict__ dout, int N_)
{
  int n = blockIdx.x * (blockDim.x >> 6) + (threadIdx.x >> 6);
  int lane = threadIdx.x & 63;
  if (n >= N_) return;
  int s = noff[n], t1 = noff[n + 1];
  float4 ns = node_soft[n];
  float2 acc = {0.0f, 0.0f};
  for (int t = s; t < t1; ++t) {
    int e = eidx_n[t];
    float l = ns.x + s_e[e];
    l = l >= 0.0f ? l : NEG_SLOPE * l;
    float ex = __expf(l - ns.y);
    uint u = eo[(size_t)e * (DIM / 2) + lane];
    acc.x = fmaf(ex, bf_lo(u), acc.x);
    acc.y = fmaf(ex, bf_hi(u), acc.y);
  }
  float sc = ns.z * ns.w;
  float2 b = ((const float2*)bias)[lane];
  size_t idx = (size_t)n * DIM + lane * 2;
  float cx = cur[idx], cy = cur[idx + 1];
  cx += acc.x * sc + b.x;
  cy += acc.y * sc + b.y;
  cur[idx] = cx; cur[idx + 1] = cy;
  dout[idx] += cx; dout[idx + 1] += cy;
}

// ---------------------------------------------------------------------------
__global__ void initcopy_kernel(const float4* __restrict__ p,
                                float4* __restrict__ cur, float4* __restrict__ dout,
                                int n4)
{
  int i = blockIdx.x * blockDim.x + threadIdx.x;
  if (i >= n4) return;
  float4 v = p[i];
  cur[i] = v;
  dout[i] = v;
}

__global__ void scale_kernel(float4* __restrict__ dout, int n4)
{
  int i = blockIdx.x * blockDim.x + threadIdx.x;
  if (i >= n4) return;
  float4 v = dout[i];
  v.x *= 0.25f; v.y *= 0.25f; v.z *= 0.25f; v.w *= 0.25f;
  dout[i] = v;
}

// ---------------------------------------------------------------------------
static inline int cdiv(int a, int b) { return (a + b - 1) / b; }

extern "C" void kernel_launch(void* const* d_in, const int* in_sizes, int n_in,
                              void* d_out, int out_size, void* d_ws, size_t ws_size,
                              hipStream_t stream)
{
  const float* pois = (const float*)d_in[0];
  const float* traj = (const float*)d_in[1];
  const float* hw   = (const float*)d_in[2];
  const int* node_idx = (const int*)d_in[3];
  const int* edge_idx = (const int*)d_in[4];
  const float* W    = (const float*)d_in[5];
  const float* att  = (const float*)d_in[6];
  const float* bias = (const float*)d_in[7];
  float* dout = (float*)d_out;

  const int N   = in_sizes[0] / DIM;
  const int M   = in_sizes[2];
  const int NNZ = in_sizes[3];

  char* p = (char*)d_ws;
  auto alloc = [&](size_t bytes) -> void* {
    void* r = (void*)p;
    p += (bytes + 255) & ~(size_t)255;
    return r;
  };
  ushort* xt_bf = (ushort*)alloc((size_t)N * DIM * 2);      // 25.6 MB
  uint*   eo_bf = (uint*)alloc((size_t)M * (DIM / 2) * 4);  //  5.1 MB
  float*  cur   = (float*)alloc((size_t)N * DIM * 4);       // 51.2 MB
  float4* node_soft = (float4*)alloc((size_t)N * 16);       //  1.6 MB
  float*  s_e  = (float*)alloc((size_t)M * 4);
  float*  s_n  = (float*)alloc((size_t)N * 4);
  float*  Dinv = (float*)alloc((size_t)N * 4);
  float*  wv2  = (float*)alloc(DIM * 4);
  int* ecnt = (int*)alloc((size_t)M * 4);
  int* ncnt = (int*)alloc((size_t)N * 4);
  int* eoff = (int*)alloc((size_t)(M + 1) * 4);
  int* noff = (int*)alloc((size_t)(N + 1) * 4);
  int* r_e  = (int*)alloc((size_t)NNZ * 4);
  int* r_n  = (int*)alloc((size_t)NNZ * 4);
  int* nd_e   = (int*)alloc((size_t)NNZ * 4);
  int* eidx_n = (int*)alloc((size_t)NNZ * 4);
  int* part_e = (int*)alloc(65 * 4);
  int* part_n = (int*)alloc(65 * 4);
  (void)ws_size;

  const int nbE = cdiv(M, 4096), nbN = cdiv(N, 4096);  // 5, 25 (<= 64)

  // ---- incidence structure (layer-invariant) ----
  hipMemsetAsync(ecnt, 0, (size_t)M * 4, stream);
  hipMemsetAsync(ncnt, 0, (size_t)N * 4, stream);
  hist_rank_kernel<<<cdiv(NNZ, 256), 256, 0, stream>>>(node_idx, edge_idx, ncnt, ecnt, r_n, r_e, NNZ);
  scan_block_kernel<<<nbE, 1024, 0, stream>>>(ecnt, eoff, part_e, M);
  scan_block_kernel<<<nbN, 1024, 0, stream>>>(ncnt, noff, part_n, N);
  scan_partials_kernel<<<1, 64, 0, stream>>>(part_e, nbE);
  scan_partials_kernel<<<1, 64, 0, stream>>>(part_n, nbN);
  add_off_kernel<<<cdiv(M, 256), 256, 0, stream>>>(eoff, part_e, M, nbE);
  add_off_kernel<<<cdiv(N, 256), 256, 0, stream>>>(noff, part_n, N, nbN);
  scatter_edge_kernel<<<cdiv(NNZ, 256), 256, 0, stream>>>(node_idx, edge_idx, r_e, eoff, nd_e, NNZ);
  scatter_node_kernel<<<cdiv(NNZ, 256), 256, 0, stream>>>(node_idx, edge_idx, r_n, noff, eidx_n, NNZ);
  ddeg_kernel<<<cdiv(N, 256), 256, 0, stream>>>(noff, eidx_n, hw, Dinv, N);

  // ---- layer-invariant dense work: s_e = traj @ (W @ att2) ----
  rowdot_kernel<<<cdiv(DIM, 4), 256, 0, stream>>>(W, att + DIM, wv2, DIM);
  rowdot_kernel<<<cdiv(M, 4), 256, 0, stream>>>(traj, wv2, s_e, M);

  // ---- init cur / accumulator ----
  int n4 = (N * DIM) / 4;
  initcopy_kernel<<<cdiv(n4, 256), 256, 0, stream>>>((const float4*)pois, (float4*)cur, (float4*)dout, n4);

  // ---- layers ----
  for (int layer = 0; layer < 3; ++layer) {
    gemm128_kernel<<<cdiv(N, 32), 256, 0, stream>>>(cur, W, att, xt_bf, s_n, N);
    softstat_kernel<<<cdiv(N, 256), 256, 0, stream>>>(noff, eidx_n, s_n, s_e, Dinv, node_soft, N);
    msg1_kernel<<<cdiv(M, 4), 256, 0, stream>>>(eoff, nd_e, node_soft, s_e, xt_bf, eo_bf, M);
    msg2_kernel<<<cdiv(N, 4), 256, 0, stream>>>(noff, eidx_n, node_soft, s_e, eo_bf, bias, cur, dout, N);
  }

  scale_kernel<<<cdiv(n4, 256), 256, 0, stream>>>((float4*)dout, n4);
}

// Round 4
// 854.591 us; speedup vs baseline: 2.3736x; 1.4069x over previous
//
#include <hip/hip_runtime.h>
#include <cstdint>
#include <cstddef>

#define DIM 128
#define NEG_SLOPE 0.2f

// ---- bf16 helpers (manual, RNE) -------------------------------------------
__device__ __forceinline__ float bf_lo(uint u) { return __uint_as_float(u << 16); }
__device__ __forceinline__ float bf_hi(uint u) { return __uint_as_float(u & 0xffff0000u); }
__device__ __forceinline__ uint f2bf(float f) {
  uint u = __float_as_uint(f);
  return (u + 0x7fffu + ((u >> 16) & 1u)) >> 16;
}
__device__ __forceinline__ uint pack_bf2(float lo, float hi) {
  return f2bf(lo) | (f2bf(hi) << 16);
}
__device__ __forceinline__ float lrelu(float x) {
  return x >= 0.0f ? x : NEG_SLOPE * x;
}

// ---------------------------------------------------------------------------
// GEMM: Y_bf16[rows x 128] = X[rows x 128] @ W[128 x 128] (fp32 compute),
// fused epilogue: s_n[row] = dot(Y_fp32[row,:], att[0:128]).
// ---------------------------------------------------------------------------
__global__ __launch_bounds__(256) void gemm128_kernel(
    const float* __restrict__ X, const float* __restrict__ W,
    const float* __restrict__ att, ushort* __restrict__ Yb,
    float* __restrict__ s_n, int rows)
{
  __shared__ float Wl[128 * 128];
  __shared__ float Xl[32 * 128];
  int tid = threadIdx.x;
  {
    const float4* W4 = (const float4*)W;
    float4* Wl4 = (float4*)Wl;
#pragma unroll
    for (int i = 0; i < 16; ++i) Wl4[tid + i * 256] = W4[tid + i * 256];
  }
  int r0 = blockIdx.x * 32;
  int nrow = rows - r0; if (nrow > 32) nrow = 32;
  {
    const float4* X4 = (const float4*)(X + (size_t)r0 * DIM);
    float4* Xl4 = (float4*)Xl;
    for (int i = tid; i < nrow * 32; i += 256) Xl4[i] = X4[i];
  }
  __syncthreads();
  int rq = (tid >> 5) << 2;
  int dg = (tid & 31) << 2;
  float4 a0 = {0,0,0,0}, a1 = a0, a2 = a0, a3 = a0;
#pragma unroll 4
  for (int k = 0; k < 128; ++k) {
    float4 w = *(const float4*)&Wl[k * 128 + dg];
    float x0 = Xl[(rq + 0) * 128 + k];
    float x1 = Xl[(rq + 1) * 128 + k];
    float x2 = Xl[(rq + 2) * 128 + k];
    float x3 = Xl[(rq + 3) * 128 + k];
    a0.x = fmaf(x0, w.x, a0.x); a0.y = fmaf(x0, w.y, a0.y);
    a0.z = fmaf(x0, w.z, a0.z); a0.w = fmaf(x0, w.w, a0.w);
    a1.x = fmaf(x1, w.x, a1.x); a1.y = fmaf(x1, w.y, a1.y);
    a1.z = fmaf(x1, w.z, a1.z); a1.w = fmaf(x1, w.w, a1.w);
    a2.x = fmaf(x2, w.x, a2.x); a2.y = fmaf(x2, w.y, a2.y);
    a2.z = fmaf(x2, w.z, a2.z); a2.w = fmaf(x2, w.w, a2.w);
    a3.x = fmaf(x3, w.x, a3.x); a3.y = fmaf(x3, w.y, a3.y);
    a3.z = fmaf(x3, w.z, a3.z); a3.w = fmaf(x3, w.w, a3.w);
  }
  ushort4 h;
#define STORE_BF(acc, r) \
  if (r0 + (r) < rows) { \
    h.x = (ushort)f2bf(acc.x); h.y = (ushort)f2bf(acc.y); \
    h.z = (ushort)f2bf(acc.z); h.w = (ushort)f2bf(acc.w); \
    *(ushort4*)&Yb[(size_t)(r0 + (r)) * DIM + dg] = h; }
  STORE_BF(a0, rq + 0)
  STORE_BF(a1, rq + 1)
  STORE_BF(a2, rq + 2)
  STORE_BF(a3, rq + 3)
#undef STORE_BF
  float4 av = *(const float4*)&att[dg];
  float s0 = a0.x*av.x + a0.y*av.y + a0.z*av.z + a0.w*av.w;
  float s1 = a1.x*av.x + a1.y*av.y + a1.z*av.z + a1.w*av.w;
  float s2 = a2.x*av.x + a2.y*av.y + a2.z*av.z + a2.w*av.w;
  float s3 = a3.x*av.x + a3.y*av.y + a3.z*av.z + a3.w*av.w;
#pragma unroll
  for (int m = 16; m >= 1; m >>= 1) {
    s0 += __shfl_xor(s0, m, 64);
    s1 += __shfl_xor(s1, m, 64);
    s2 += __shfl_xor(s2, m, 64);
    s3 += __shfl_xor(s3, m, 64);
  }
  if ((tid & 31) == 0) {
    if (r0 + rq + 0 < rows) s_n[r0 + rq + 0] = s0;
    if (r0 + rq + 1 < rows) s_n[r0 + rq + 1] = s1;
    if (r0 + rq + 2 < rows) s_n[r0 + rq + 2] = s2;
    if (r0 + rq + 3 < rows) s_n[r0 + rq + 3] = s3;
  }
}

// ---------------------------------------------------------------------------
__global__ __launch_bounds__(256) void rowdot_kernel(
    const float* __restrict__ X, const float* __restrict__ a,
    float* __restrict__ out, int rows)
{
  int w = blockIdx.x * (blockDim.x >> 6) + (threadIdx.x >> 6);
  int lane = threadIdx.x & 63;
  if (w >= rows) return;
  const float* row = X + (size_t)w * DIM;
  float v = row[lane] * a[lane] + row[lane + 64] * a[lane + 64];
#pragma unroll
  for (int d = 32; d > 0; d >>= 1) v += __shfl_down(v, d, 64);
  if (lane == 0) out[w] = v;
}

// ---------------------------------------------------------------------------
// Rank-fused histogram: counts AND within-segment ranks in one pass.
// ---------------------------------------------------------------------------
__global__ void hist_rank_kernel(const int* __restrict__ node_idx,
                                 const int* __restrict__ edge_idx,
                                 int* __restrict__ ncnt, int* __restrict__ ecnt,
                                 int* __restrict__ r_n, int* __restrict__ r_e,
                                 int nnz)
{
  int j = blockIdx.x * blockDim.x + threadIdx.x;
  if (j >= nnz) return;
  r_e[j] = atomicAdd(&ecnt[edge_idx[j]], 1);
  r_n[j] = atomicAdd(&ncnt[node_idx[j]], 1);
}

// ---------------------------------------------------------------------------
// Two-level exclusive scan
// ---------------------------------------------------------------------------
__global__ __launch_bounds__(1024) void scan_block_kernel(
    const int* __restrict__ cnt, int* __restrict__ off,
    int* __restrict__ partials, int nbins)
{
  __shared__ int ws[16];
  int tid = threadIdx.x, lane = tid & 63, wid = tid >> 6;
  int base = blockIdx.x * 4096 + tid * 4;
  int x0 = base + 0 < nbins ? cnt[base + 0] : 0;
  int x1 = base + 1 < nbins ? cnt[base + 1] : 0;
  int x2 = base + 2 < nbins ? cnt[base + 2] : 0;
  int x3 = base + 3 < nbins ? cnt[base + 3] : 0;
  int t = x0 + x1 + x2 + x3;
  int v = t;
#pragma unroll
  for (int d = 1; d < 64; d <<= 1) {
    int y = __shfl_up(v, d, 64);
    if (lane >= d) v += y;
  }
  if (lane == 63) ws[wid] = v;
  __syncthreads();
  if (tid < 16) {
    int s = ws[tid];
#pragma unroll
    for (int d = 1; d < 16; d <<= 1) {
      int y = __shfl_up(s, d, 16);
      if (tid >= d) s += y;
    }
    ws[tid] = s;
  }
  __syncthreads();
  int pre = (wid > 0 ? ws[wid - 1] : 0) + (v - t);
  if (base + 0 < nbins) off[base + 0] = pre;
  if (base + 1 < nbins) off[base + 1] = pre + x0;
  if (base + 2 < nbins) off[base + 2] = pre + x0 + x1;
  if (base + 3 < nbins) off[base + 3] = pre + x0 + x1 + x2;
  if (tid == 0) partials[blockIdx.x] = ws[15];
}

__global__ __launch_bounds__(64) void scan_partials_kernel(
    int* __restrict__ partials, int nb)
{
  int lane = threadIdx.x;
  int t = lane < nb ? partials[lane] : 0;
  int v = t;
#pragma unroll
  for (int d = 1; d < 64; d <<= 1) {
    int y = __shfl_up(v, d, 64);
    if (lane >= d) v += y;
  }
  if (lane < nb) partials[lane] = v - t;
  if (lane == 63) partials[nb] = v;
}

__global__ void add_off_kernel(int* __restrict__ off,
                               const int* __restrict__ partials,
                               int nbins, int nb)
{
  int i = blockIdx.x * blockDim.x + threadIdx.x;
  if (i < nbins) off[i] += partials[i >> 12];
  if (i == 0) off[nbins] = partials[nb];
}

// ---------------------------------------------------------------------------
// Atomic-free CSR scatters (payload-carrying)
// ---------------------------------------------------------------------------
__global__ void scatter_edge_kernel(const int* __restrict__ node_idx,
                                    const int* __restrict__ edge_idx,
                                    const int* __restrict__ r_e,
                                    const int* __restrict__ eoff,
                                    int* __restrict__ nd_e, int nnz)
{
  int j = blockIdx.x * blockDim.x + threadIdx.x;
  if (j >= nnz) return;
  int e = edge_idx[j];
  nd_e[eoff[e] + r_e[j]] = node_idx[j];
}

__global__ void scatter_node_kernel(const int* __restrict__ node_idx,
                                    const int* __restrict__ edge_idx,
                                    const int* __restrict__ r_n,
                                    const int* __restrict__ noff,
                                    int* __restrict__ eidx_n, int nnz)
{
  int j = blockIdx.x * blockDim.x + threadIdx.x;
  if (j >= nnz) return;
  int n = node_idx[j];
  eidx_n[noff[n] + r_n[j]] = edge_idx[j];
}

// ---------------------------------------------------------------------------
// pack se_hw[e] = {s_e[e], hw[e]} so softstat gathers once per incidence
// ---------------------------------------------------------------------------
__global__ void pack_sehw_kernel(const float* __restrict__ s_e,
                                 const float* __restrict__ hw,
                                 float2* __restrict__ se_hw, int M_)
{
  int e = blockIdx.x * blockDim.x + threadIdx.x;
  if (e >= M_) return;
  float2 g; g.x = s_e[e]; g.y = hw[e];
  se_hw[e] = g;
}

// ---------------------------------------------------------------------------
// Per-node online softmax stats + weighted degree (fused, 4x unrolled MLP):
// node_soft[n] = {s_n, m, 1/(den+1e-16), 1/Ddeg}
// ---------------------------------------------------------------------------
__global__ void softstat_kernel(const int* __restrict__ noff,
                                const int* __restrict__ eidx_n,
                                const float* __restrict__ s_n,
                                const float2* __restrict__ se_hw,
                                float4* __restrict__ node_soft, int N_)
{
  int n = blockIdx.x * blockDim.x + threadIdx.x;
  if (n >= N_) return;
  int s = noff[n], e1 = noff[n + 1];
  float sn = s_n[n];
  float m = -INFINITY, den = 0.0f, d = 0.0f;
  int t = s;
  for (; t + 4 <= e1; t += 4) {
    int i0 = eidx_n[t], i1 = eidx_n[t + 1], i2 = eidx_n[t + 2], i3 = eidx_n[t + 3];
    float2 g0 = se_hw[i0], g1 = se_hw[i1], g2 = se_hw[i2], g3 = se_hw[i3];
    float l0 = lrelu(sn + g0.x), l1 = lrelu(sn + g1.x);
    float l2 = lrelu(sn + g2.x), l3 = lrelu(sn + g3.x);
    float mm = fmaxf(fmaxf(fmaxf(l0, l1), fmaxf(l2, l3)), m);
    den = den * __expf(m - mm) + __expf(l0 - mm) + __expf(l1 - mm)
        + __expf(l2 - mm) + __expf(l3 - mm);
    m = mm;
    d += g0.y + g1.y + g2.y + g3.y;
  }
  for (; t < e1; ++t) {
    float2 g = se_hw[eidx_n[t]];
    float l = lrelu(sn + g.x);
    float mm = fmaxf(l, m);
    den = den * __expf(m - mm) + __expf(l - mm);
    m = mm;
    d += g.y;
  }
  if (s == e1) m = 0.0f;
  float4 r;
  r.x = sn; r.y = m; r.z = 1.0f / (den + 1e-16f);
  r.w = d > 0.0f ? 1.0f / d : 0.0f;
  node_soft[n] = r;
}

// ---------------------------------------------------------------------------
// msg1: eo_bf16[e,:] = (1/|e|) * sum_{j in e} alpha_j * xt_bf16[nd_j,:]
// one wave per edge; 4x unrolled for gather MLP.
// ---------------------------------------------------------------------------
__global__ __launch_bounds__(256) void msg1_kernel(
    const int* __restrict__ eoff, const int* __restrict__ nd_e,
    const float4* __restrict__ node_soft, const float* __restrict__ s_e,
    const ushort* __restrict__ xt, uint* __restrict__ eo, int M_)
{
  int e = blockIdx.x * (blockDim.x >> 6) + (threadIdx.x >> 6);
  int lane = threadIdx.x & 63;
  if (e >= M_) return;
  int s = eoff[e], t1 = eoff[e + 1];
  int len = t1 - s;
  float binv = len > 0 ? 1.0f / (float)len : 0.0f;
  float se = s_e[e];
  const uint* xt4 = (const uint*)xt + lane;
  float2 acc = {0.0f, 0.0f};
  int t = s;
  for (; t + 4 <= t1; t += 4) {
    int n0 = nd_e[t], n1 = nd_e[t + 1], n2 = nd_e[t + 2], n3 = nd_e[t + 3];
    float4 q0 = node_soft[n0];
    float4 q1 = node_soft[n1];
    float4 q2 = node_soft[n2];
    float4 q3 = node_soft[n3];
    uint u0 = xt4[(size_t)n0 * 64];
    uint u1 = xt4[(size_t)n1 * 64];
    uint u2 = xt4[(size_t)n2 * 64];
    uint u3 = xt4[(size_t)n3 * 64];
    float c0 = __expf(lrelu(q0.x + se) - q0.y) * q0.z;
    float c1 = __expf(lrelu(q1.x + se) - q1.y) * q1.z;
    float c2 = __expf(lrelu(q2.x + se) - q2.y) * q2.z;
    float c3 = __expf(lrelu(q3.x + se) - q3.y) * q3.z;
    acc.x = fmaf(c0, bf_lo(u0), acc.x); acc.y = fmaf(c0, bf_hi(u0), acc.y);
    acc.x = fmaf(c1, bf_lo(u1), acc.x); acc.y = fmaf(c1, bf_hi(u1), acc.y);
    acc.x = fmaf(c2, bf_lo(u2), acc.x); acc.y = fmaf(c2, bf_hi(u2), acc.y);
    acc.x = fmaf(c3, bf_lo(u3), acc.x); acc.y = fmaf(c3, bf_hi(u3), acc.y);
  }
  for (; t < t1; ++t) {
    int nd = nd_e[t];
    float4 q = node_soft[nd];
    uint u = xt4[(size_t)nd * 64];
    float c = __expf(lrelu(q.x + se) - q.y) * q.z;
    acc.x = fmaf(c, bf_lo(u), acc.x);
    acc.y = fmaf(c, bf_hi(u), acc.y);
  }
  eo[(size_t)e * (DIM / 2) + lane] = pack_bf2(acc.x * binv, acc.y * binv);
}

// ---------------------------------------------------------------------------
// msg2 fused with residual + stack accumulation. One wave per node; 4x unroll.
// ---------------------------------------------------------------------------
__global__ __launch_bounds__(256) void msg2_kernel(
    const int* __restrict__ noff, const int* __restrict__ eidx_n,
    const float4* __restrict__ node_soft, const float* __restrict__ s_e,
    const uint* __restrict__ eo, const float* __restrict__ bias,
    float* __restrict__ cur, float* __restrict__ dout, int N_)
{
  int n = blockIdx.x * (blockDim.x >> 6) + (threadIdx.x >> 6);
  int lane = threadIdx.x & 63;
  if (n >= N_) return;
  int s = noff[n], t1 = noff[n + 1];
  float4 ns = node_soft[n];
  const uint* eo4 = eo + lane;
  float2 acc = {0.0f, 0.0f};
  int t = s;
  for (; t + 4 <= t1; t += 4) {
    int e0 = eidx_n[t], e1 = eidx_n[t + 1], e2 = eidx_n[t + 2], e3 = eidx_n[t + 3];
    float x0 = s_e[e0], x1 = s_e[e1], x2 = s_e[e2], x3 = s_e[e3];
    uint u0 = eo4[(size_t)e0 * 64];
    uint u1 = eo4[(size_t)e1 * 64];
    uint u2 = eo4[(size_t)e2 * 64];
    uint u3 = eo4[(size_t)e3 * 64];
    float c0 = __expf(lrelu(ns.x + x0) - ns.y);
    float c1 = __expf(lrelu(ns.x + x1) - ns.y);
    float c2 = __expf(lrelu(ns.x + x2) - ns.y);
    float c3 = __expf(lrelu(ns.x + x3) - ns.y);
    acc.x = fmaf(c0, bf_lo(u0), acc.x); acc.y = fmaf(c0, bf_hi(u0), acc.y);
    acc.x = fmaf(c1, bf_lo(u1), acc.x); acc.y = fmaf(c1, bf_hi(u1), acc.y);
    acc.x = fmaf(c2, bf_lo(u2), acc.x); acc.y = fmaf(c2, bf_hi(u2), acc.y);
    acc.x = fmaf(c3, bf_lo(u3), acc.x); acc.y = fmaf(c3, bf_hi(u3), acc.y);
  }
  for (; t < t1; ++t) {
    int e = eidx_n[t];
    uint u = eo4[(size_t)e * 64];
    float c = __expf(lrelu(ns.x + s_e[e]) - ns.y);
    acc.x = fmaf(c, bf_lo(u), acc.x);
    acc.y = fmaf(c, bf_hi(u), acc.y);
  }
  float sc = ns.z * ns.w;
  float2 b = ((const float2*)bias)[lane];
  size_t idx = (size_t)n * DIM + lane * 2;
  float cx = cur[idx], cy = cur[idx + 1];
  cx += acc.x * sc + b.x;
  cy += acc.y * sc + b.y;
  cur[idx] = cx; cur[idx + 1] = cy;
  dout[idx] += cx; dout[idx + 1] += cy;
}

// ---------------------------------------------------------------------------
__global__ void initcopy_kernel(const float4* __restrict__ p,
                                float4* __restrict__ cur, float4* __restrict__ dout,
                                int n4)
{
  int i = blockIdx.x * blockDim.x + threadIdx.x;
  if (i >= n4) return;
  float4 v = p[i];
  cur[i] = v;
  dout[i] = v;
}

__global__ void scale_kernel(float4* __restrict__ dout, int n4)
{
  int i = blockIdx.x * blockDim.x + threadIdx.x;
  if (i >= n4) return;
  float4 v = dout[i];
  v.x *= 0.25f; v.y *= 0.25f; v.z *= 0.25f; v.w *= 0.25f;
  dout[i] = v;
}

// ---------------------------------------------------------------------------
static inline int cdiv(int a, int b) { return (a + b - 1) / b; }

extern "C" void kernel_launch(void* const* d_in, const int* in_sizes, int n_in,
                              void* d_out, int out_size, void* d_ws, size_t ws_size,
                              hipStream_t stream)
{
  const float* pois = (const float*)d_in[0];
  const float* traj = (const float*)d_in[1];
  const float* hw   = (const float*)d_in[2];
  const int* node_idx = (const int*)d_in[3];
  const int* edge_idx = (const int*)d_in[4];
  const float* W    = (const float*)d_in[5];
  const float* att  = (const float*)d_in[6];
  const float* bias = (const float*)d_in[7];
  float* dout = (float*)d_out;

  const int N   = in_sizes[0] / DIM;
  const int M   = in_sizes[2];
  const int NNZ = in_sizes[3];

  char* p = (char*)d_ws;
  auto alloc = [&](size_t bytes) -> void* {
    void* r = (void*)p;
    p += (bytes + 255) & ~(size_t)255;
    return r;
  };
  ushort* xt_bf = (ushort*)alloc((size_t)N * DIM * 2);
  uint*   eo_bf = (uint*)alloc((size_t)M * (DIM / 2) * 4);
  float*  cur   = (float*)alloc((size_t)N * DIM * 4);
  float4* node_soft = (float4*)alloc((size_t)N * 16);
  float*  s_e  = (float*)alloc((size_t)M * 4);
  float2* se_hw = (float2*)alloc((size_t)M * 8);
  float*  s_n  = (float*)alloc((size_t)N * 4);
  float*  wv2  = (float*)alloc(DIM * 4);
  int* ecnt = (int*)alloc((size_t)M * 4);
  int* ncnt = (int*)alloc((size_t)N * 4);
  int* eoff = (int*)alloc((size_t)(M + 1) * 4);
  int* noff = (int*)alloc((size_t)(N + 1) * 4);
  int* r_e  = (int*)alloc((size_t)NNZ * 4);
  int* r_n  = (int*)alloc((size_t)NNZ * 4);
  int* nd_e   = (int*)alloc((size_t)NNZ * 4);
  int* eidx_n = (int*)alloc((size_t)NNZ * 4);
  int* part_e = (int*)alloc(65 * 4);
  int* part_n = (int*)alloc(65 * 4);
  (void)ws_size;

  const int nbE = cdiv(M, 4096), nbN = cdiv(N, 4096);

  // ---- incidence structure (layer-invariant) ----
  hipMemsetAsync(ecnt, 0, (size_t)M * 4, stream);
  hipMemsetAsync(ncnt, 0, (size_t)N * 4, stream);
  hist_rank_kernel<<<cdiv(NNZ, 256), 256, 0, stream>>>(node_idx, edge_idx, ncnt, ecnt, r_n, r_e, NNZ);
  scan_block_kernel<<<nbE, 1024, 0, stream>>>(ecnt, eoff, part_e, M);
  scan_block_kernel<<<nbN, 1024, 0, stream>>>(ncnt, noff, part_n, N);
  scan_partials_kernel<<<1, 64, 0, stream>>>(part_e, nbE);
  scan_partials_kernel<<<1, 64, 0, stream>>>(part_n, nbN);
  add_off_kernel<<<cdiv(M, 256), 256, 0, stream>>>(eoff, part_e, M, nbE);
  add_off_kernel<<<cdiv(N, 256), 256, 0, stream>>>(noff, part_n, N, nbN);
  scatter_edge_kernel<<<cdiv(NNZ, 256), 256, 0, stream>>>(node_idx, edge_idx, r_e, eoff, nd_e, NNZ);
  scatter_node_kernel<<<cdiv(NNZ, 256), 256, 0, stream>>>(node_idx, edge_idx, r_n, noff, eidx_n, NNZ);

  // ---- layer-invariant dense work: s_e = traj @ (W @ att2) ----
  rowdot_kernel<<<cdiv(DIM, 4), 256, 0, stream>>>(W, att + DIM, wv2, DIM);
  rowdot_kernel<<<cdiv(M, 4), 256, 0, stream>>>(traj, wv2, s_e, M);
  pack_sehw_kernel<<<cdiv(M, 256), 256, 0, stream>>>(s_e, hw, se_hw, M);

  // ---- init cur / accumulator ----
  int n4 = (N * DIM) / 4;
  initcopy_kernel<<<cdiv(n4, 256), 256, 0, stream>>>((const float4*)pois, (float4*)cur, (float4*)dout, n4);

  // ---- layers ----
  for (int layer = 0; layer < 3; ++layer) {
    gemm128_kernel<<<cdiv(N, 32), 256, 0, stream>>>(cur, W, att, xt_bf, s_n, N);
    softstat_kernel<<<cdiv(N, 256), 256, 0, stream>>>(noff, eidx_n, s_n, se_hw, node_soft, N);
    msg1_kernel<<<cdiv(M, 4), 256, 0, stream>>>(eoff, nd_e, node_soft, s_e, xt_bf, eo_bf, M);
    msg2_kernel<<<cdiv(N, 4), 256, 0, stream>>>(noff, eidx_n, node_soft, s_e, eo_bf, bias, cur, dout, N);
  }

  scale_kernel<<<cdiv(n4, 256), 256, 0, stream>>>((float4*)dout, n4);
}